// Round 13
// baseline (299.484 us; speedup 1.0000x reference)
//
#include <hip/hip_runtime.h>

#define NB 131072
#define NEG9 -1e9f

typedef __attribute__((ext_vector_type(8))) __bf16 bf16x8;
typedef __attribute__((ext_vector_type(4))) float f32x4;
typedef __attribute__((ext_vector_type(2))) unsigned int u32x2;
typedef __attribute__((ext_vector_type(4))) unsigned int u32x4;

__device__ __forceinline__ f32x4 mfma16(bf16x8 a, bf16x8 b, f32x4 c) {
    return __builtin_amdgcn_mfma_f32_16x16x32_bf16(a, b, c, 0, 0, 0);
}

// pack two floats to bf16x2 (truncation) in ONE v_perm_b32: [hi16(h) | hi16(l)]
__device__ __forceinline__ unsigned pk(float h, float l) {
    return __builtin_amdgcn_perm(__builtin_bit_cast(unsigned, h),
                                 __builtin_bit_cast(unsigned, l), 0x07060302u);
}
__device__ __forceinline__ unsigned pku(unsigned h, unsigned l) {
    return __builtin_amdgcn_perm(h, l, 0x07060302u);
}

// float -> bf16 (RNE) for weight prep
__device__ __forceinline__ unsigned short f2bf(float f) {
    unsigned u = __builtin_bit_cast(unsigned, f);
    u += 0x7fffu + ((u >> 16) & 1u);
    return (unsigned short)(u >> 16);
}

// BN-folded, transposed (n-major, k-contiguous) bf16 weights + fp32 biases.
struct __align__(16) Wspace {
    unsigned short W0t[512][64];
    unsigned short W1t[256][512];
    unsigned short nW1t[64][256];
    unsigned short dW1t[64][256];
    unsigned short nW2t[128][64];
    unsigned short dW2t[128][64];
    float c0[512];
    float c1[256];
    float nb1c[64], db1c[64];
    float nb2c[128], db2c[128];
};

__device__ Wspace g_ws;

// r11 prep: 64x64 LDS-transpose tiles, fully coalesced both sides (kept).
__global__ __launch_bounds__(256) void prep_kernel(
    const float* __restrict__ W0, const float* __restrict__ b0,
    const float* __restrict__ g0, const float* __restrict__ be0,
    const float* __restrict__ rm0, const float* __restrict__ rv0,
    const float* __restrict__ W1, const float* __restrict__ b1,
    const float* __restrict__ g1, const float* __restrict__ be1,
    const float* __restrict__ rm1, const float* __restrict__ rv1,
    const float* __restrict__ nW1, const float* __restrict__ nb1,
    const float* __restrict__ nW2, const float* __restrict__ nb2,
    const float* __restrict__ dW1, const float* __restrict__ db1,
    const float* __restrict__ dW2, const float* __restrict__ db2)
{
    const int b = blockIdx.x;
    const int t = threadIdx.x;

    if (b == 52) {  // bias / BN-constant vectors (all coalesced)
        {   // c0[512]
            int i = t;          g_ws.c0[i] = (b0[i] - rm0[i]) * (g0[i] * rsqrtf(rv0[i] + 1e-5f)) + be0[i];
            i = t + 256;        g_ws.c0[i] = (b0[i] - rm0[i]) * (g0[i] * rsqrtf(rv0[i] + 1e-5f)) + be0[i];
        }
        g_ws.c1[t] = (b1[t] - rm1[t]) * (g1[t] * rsqrtf(rv1[t] + 1e-5f)) + be1[t];
        if (t < 64)  { g_ws.nb1c[t] = nb1[t]; g_ws.db1c[t] = db1[t]; }
        if (t < 128) { g_ws.nb2c[t] = nb2[t]; g_ws.db2c[t] = db2[t]; }
        return;
    }

    const float* src; unsigned short* dst;
    const float* gp = nullptr; const float* rvp = nullptr;
    int sld, dld, k0, n0;
    if (b < 32)      { src = W1;  dst = (unsigned short*)g_ws.W1t;  sld = 256; dld = 512;
                       k0 = (b >> 2) * 64; n0 = (b & 3) * 64; gp = g1; rvp = rv1; }
    else if (b < 40) { src = W0;  dst = (unsigned short*)g_ws.W0t;  sld = 512; dld = 64;
                       k0 = 0; n0 = (b - 32) * 64; gp = g0; rvp = rv0; }
    else if (b < 44) { src = nW1; dst = (unsigned short*)g_ws.nW1t; sld = 64;  dld = 256;
                       k0 = (b - 40) * 64; n0 = 0; }
    else if (b < 48) { src = dW1; dst = (unsigned short*)g_ws.dW1t; sld = 64;  dld = 256;
                       k0 = (b - 44) * 64; n0 = 0; }
    else if (b < 50) { src = nW2; dst = (unsigned short*)g_ws.nW2t; sld = 128; dld = 64;
                       k0 = 0; n0 = (b - 48) * 64; }
    else             { src = dW2; dst = (unsigned short*)g_ws.dW2t; sld = 128; dld = 64;
                       k0 = 0; n0 = (b - 50) * 64; }

    __shared__ unsigned short tile[64][66];

    const int rr = t >> 4;
    const int cc = (t & 15) * 4;

#pragma unroll
    for (int g = 0; g < 4; ++g) {
        const int r = rr + g * 16;
        f32x4 v = *(const f32x4*)&src[(size_t)(k0 + r) * sld + n0 + cc];
        if (gp) {
            f32x4 gv = *(const f32x4*)&gp[n0 + cc];
            f32x4 rv = *(const f32x4*)&rvp[n0 + cc];
            v[0] *= gv[0] * rsqrtf(rv[0] + 1e-5f);
            v[1] *= gv[1] * rsqrtf(rv[1] + 1e-5f);
            v[2] *= gv[2] * rsqrtf(rv[2] + 1e-5f);
            v[3] *= gv[3] * rsqrtf(rv[3] + 1e-5f);
        }
        *(unsigned*)&tile[r][cc]     = (unsigned)f2bf(v[0]) | ((unsigned)f2bf(v[1]) << 16);
        *(unsigned*)&tile[r][cc + 2] = (unsigned)f2bf(v[2]) | ((unsigned)f2bf(v[3]) << 16);
    }
    __syncthreads();

#pragma unroll
    for (int g = 0; g < 4; ++g) {
        const int n = rr + g * 16;
        unsigned o01 = (unsigned)tile[cc + 0][n] | ((unsigned)tile[cc + 1][n] << 16);
        unsigned o23 = (unsigned)tile[cc + 2][n] | ((unsigned)tile[cc + 3][n] << 16);
        u32x2 o = { o01, o23 };
        *(u32x2*)&dst[(size_t)(n0 + n) * dld + k0 + cc] = o;
    }
}

// LEDGER: r15 (128 rows/block) 134->120; r16 (L1 liveness fix) 120->104,
//   bench 255.9. Wall accounting @104us: MFMA 21% (matches counter), LDS
//   reads ~40% (now DOMINANT), L2 ~12%, spill ~44MB residual.
// r17: ROW-SPLIT the sH-consuming phases to halve wave-redundant LDS reads
//   (work/wave unchanged; each wave takes 2x cols x 1/2 rows):
//   - L1: cg=w&3 (64 cols) x rh=w>>2 (64 rows); ab reads 128->64/wave;
//     acc1[4][4] (same 64 regs); wb[4] from L2 (cached).
//   - head1: r9-proven split: head=w>>2, rh=w&1, ct2=(w>>1)&1 (32 cols x
//     64 rows); ab reads 64->32/wave; acc[2][4]=32.
//   - head2: rh=w&1, ch2=(w>>1)&1 (64 cols x 64 rows); a0/a1 hoisted over
//     ct -> reads 32->8/wave; w2f/b2f hoisted (acc1 dead, regs free).
//   L0/staging/layout/barriers unchanged. LDS reads ~1.8->0.9 MB/block.
__global__ __launch_bounds__(512, 4) void fused_mlp(
    const u32x4* __restrict__ xu, float* __restrict__ out)
{
    __shared__ __align__(16) unsigned short sXs[8 * 128 * 8];   // 16 KB (X, live to end)
    __shared__ __align__(16) unsigned short sH[32 * 128 * 8];   // 64 KB (H0 chunk / H1 / A)

    const int tid = threadIdx.x;
    const int w = tid >> 6;          // wave 0..7
    const int lane = tid & 63;
    const int m = lane & 15;
    const int q = lane >> 4;
    const int qh = q >> 1;
    const int ql = (q & 1) * 4;
    const int row0 = blockIdx.x * 128;

    // ---- stage X -> bf16 granule-major [g][r][8]; 2 units/thread ----
    {
        int r = tid >> 3, g = tid & 7;
#pragma unroll
        for (int hh = 0; hh < 2; ++hh) {
            int rr = r + hh * 64;
            u32x4 v0 = __builtin_nontemporal_load(&xu[(size_t)(row0 + rr) * 16 + g * 2]);
            u32x4 v1 = __builtin_nontemporal_load(&xu[(size_t)(row0 + rr) * 16 + g * 2 + 1]);
            u32x4 p = { pku(v0[1], v0[0]), pku(v0[3], v0[2]), pku(v1[1], v1[0]), pku(v1[3], v1[2]) };
            *(u32x4*)&sXs[(g * 128 + rr) * 8] = p;
        }
    }
    __syncthreads();   // B1

    // ---- layers 0+1, 2 K-chunks of 256; layer-1 partials in regs ----
    const int cg = w & 3;            // L1 col group: [cg*64, +64)
    const int rh = w >> 2;           // L1 row half:  [rh*64, +64)
    f32x4 acc1[4][4];                // [nt][mt]
#pragma unroll
    for (int a = 0; a < 4; ++a)
#pragma unroll
        for (int b = 0; b < 4; ++b) acc1[a][b] = f32x4{0.f, 0.f, 0.f, 0.f};

    for (int ch = 0; ch < 2; ++ch) {
        // layer0: wave w -> chunk cols [w*32,+32), ALL 128 rows (unchanged)
#pragma unroll
        for (int nt = 0; nt < 2; ++nt) {
            const int gcb = ch * 256 + w * 32 + nt * 16;
            bf16x8 wa0 = *(const bf16x8*)&g_ws.W0t[gcb + m][q * 8];
            bf16x8 wa1 = *(const bf16x8*)&g_ws.W0t[gcb + m][32 + q * 8];
            f32x4 bias = *(const f32x4*)&g_ws.c0[gcb + q * 4];
            const int kg = w * 4 + nt * 2 + qh;    // granule 0..31
#pragma unroll
            for (int mt = 0; mt < 8; ++mt) {
                bf16x8 xq0 = *(const bf16x8*)&sXs[(q * 128 + mt * 16 + m) * 8];
                bf16x8 xq1 = *(const bf16x8*)&sXs[((4 + q) * 128 + mt * 16 + m) * 8];
                f32x4 c = {0.f, 0.f, 0.f, 0.f};
                c = mfma16(wa0, xq0, c);
                c = mfma16(wa1, xq1, c);
                u32x2 pw = { pk(fmaxf(c[1] + bias[1], 0.f), fmaxf(c[0] + bias[0], 0.f)),
                             pk(fmaxf(c[3] + bias[3], 0.f), fmaxf(c[2] + bias[2], 0.f)) };
                *(u32x2*)&sH[(kg * 128 + mt * 16 + m) * 8 + ql] = pw;
            }
        }
        __syncthreads();   // B2 / B4

        // layer1 partial: wave w -> cols [cg*64,+64), rows [rh*64,+64).
        // ab reads halve vs r16 (each wave reads only its 64-row half).
#pragma unroll
        for (int ks = 0; ks < 8; ++ks) {
            bf16x8 wb0 = *(const bf16x8*)&g_ws.W1t[cg * 64 + m][ch * 256 + ks * 32 + q * 8];
            bf16x8 wb1 = *(const bf16x8*)&g_ws.W1t[cg * 64 + 16 + m][ch * 256 + ks * 32 + q * 8];
            bf16x8 wb2 = *(const bf16x8*)&g_ws.W1t[cg * 64 + 32 + m][ch * 256 + ks * 32 + q * 8];
            bf16x8 wb3 = *(const bf16x8*)&g_ws.W1t[cg * 64 + 48 + m][ch * 256 + ks * 32 + q * 8];
#pragma unroll
            for (int mt = 0; mt < 4; ++mt) {
                bf16x8 ab = *(const bf16x8*)&sH[((ks * 4 + q) * 128 + rh * 64 + mt * 16 + m) * 8];
                acc1[0][mt] = mfma16(wb0, ab, acc1[0][mt]);
                acc1[1][mt] = mfma16(wb1, ab, acc1[1][mt]);
                acc1[2][mt] = mfma16(wb2, ab, acc1[2][mt]);
                acc1[3][mt] = mfma16(wb3, ab, acc1[3][mt]);
            }
        }
        __syncthreads();   // B3 / B5
    }

    // ---- H1 = relu(acc1 + c1) -> sH: cols cg*64+nt*16, rows rh*64+mt*16 ----
#pragma unroll
    for (int nt = 0; nt < 4; ++nt) {
        const int cb = cg * 64 + nt * 16;
        f32x4 bias = *(const f32x4*)&g_ws.c1[cb + q * 4];
        const int kg = cg * 8 + nt * 2 + qh;   // granule 0..31
#pragma unroll
        for (int mt = 0; mt < 4; ++mt) {
            f32x4 c = acc1[nt][mt];
            u32x2 pw = { pk(fmaxf(c[1] + bias[1], 0.f), fmaxf(c[0] + bias[0], 0.f)),
                         pk(fmaxf(c[3] + bias[3], 0.f), fmaxf(c[2] + bias[2], 0.f)) };
            *(u32x2*)&sH[(kg * 128 + rh * 64 + mt * 16 + m) * 8 + ql] = pw;
        }
    }
    __syncthreads();   // B6

    // ---- head layer 1: head=w>>2; rh1=w&1 rows, ct2=(w>>1)&1 cols ----
    const int head = w >> 2;
    const int rh1 = w & 1;
    const int ct2 = (w >> 1) & 1;
    {
        const unsigned short (*Wh)[256] = head ? g_ws.dW1t : g_ws.nW1t;
        const float* bh = head ? g_ws.db1c : g_ws.nb1c;
        f32x4 acc[2][4];
#pragma unroll
        for (int a = 0; a < 2; ++a)
#pragma unroll
            for (int b = 0; b < 4; ++b) acc[a][b] = f32x4{0.f, 0.f, 0.f, 0.f};
#pragma unroll
        for (int ks = 0; ks < 8; ++ks) {
            bf16x8 wh0 = *(const bf16x8*)&Wh[ct2 * 32 + m][ks * 32 + q * 8];
            bf16x8 wh1 = *(const bf16x8*)&Wh[ct2 * 32 + 16 + m][ks * 32 + q * 8];
#pragma unroll
            for (int mt = 0; mt < 4; ++mt) {
                bf16x8 ab = *(const bf16x8*)&sH[((ks * 4 + q) * 128 + rh1 * 64 + mt * 16 + m) * 8];
                acc[0][mt] = mfma16(wh0, ab, acc[0][mt]);
                acc[1][mt] = mfma16(wh1, ab, acc[1][mt]);
            }
        }
        // all waves' H1 reads must finish before A overlays sH
        __syncthreads();   // B7
        unsigned short* Ah = sH + head * 8192;   // An @ [0,16KB), Ad @ [16KB,32KB)
#pragma unroll
        for (int nt = 0; nt < 2; ++nt) {
            f32x4 bias = *(const f32x4*)&bh[ct2 * 32 + nt * 16 + q * 4];
            const int kg = ct2 * 4 + nt * 2 + qh;   // granule 0..7 within head's A
#pragma unroll
            for (int mt = 0; mt < 4; ++mt) {
                f32x4 c = acc[nt][mt];
                u32x2 pw = { pk(fmaxf(c[1] + bias[1], 0.f), fmaxf(c[0] + bias[0], 0.f)),
                             pk(fmaxf(c[3] + bias[3], 0.f), fmaxf(c[2] + bias[2], 0.f)) };
                *(u32x2*)&Ah[(kg * 128 + rh1 * 64 + mt * 16 + m) * 8 + ql] = pw;
            }
        }
    }
    __syncthreads();   // B8

    // ---- head layer 2: rh1 rows, ch2=(w>>1)&1 col-half (4 ct tiles) ----
    {
        const int ch2 = (w >> 1) & 1;
        const unsigned short (*W2)[64] = head ? g_ws.dW2t : g_ws.nW2t;
        const float* b2 = head ? g_ws.db2c : g_ws.nb2c;
        const unsigned short* Ah = sH + head * 8192;
        float* op = out + (size_t)head * (size_t)NB * 128;

        // thresholds via PROVEN sXs path: granule 7 elems 4,5 = cols 60,61
        int thr[4];
#pragma unroll
        for (int mt = 0; mt < 4; ++mt) {
            unsigned tv = *(const unsigned*)&sXs[(7 * 128 + rh1 * 64 + mt * 16 + m) * 8 + 4];
            thr[mt] = (int)__builtin_bit_cast(float, head ? (tv & 0xffff0000u) : (tv << 16));
        }
        // hoist all 4 ct tiles' weights/biases (acc1 dead -> regs free)
        bf16x8 w2f[4][2];
        f32x4 b2f[4];
#pragma unroll
        for (int ct = 0; ct < 4; ++ct) {
            const int ocb = ch2 * 64 + ct * 16;
            w2f[ct][0] = *(const bf16x8*)&W2[ocb + m][q * 8];
            w2f[ct][1] = *(const bf16x8*)&W2[ocb + m][32 + q * 8];
            b2f[ct] = *(const f32x4*)&b2[ocb + q * 4];
        }
#pragma unroll
        for (int mt = 0; mt < 4; ++mt) {
            bf16x8 a0 = *(const bf16x8*)&Ah[(q * 128 + rh1 * 64 + mt * 16 + m) * 8];
            bf16x8 a1 = *(const bf16x8*)&Ah[((4 + q) * 128 + rh1 * 64 + mt * 16 + m) * 8];
            const int t = thr[mt];
            const size_t orow = (size_t)(row0 + rh1 * 64 + mt * 16 + m) * 128;
#pragma unroll
            for (int ct = 0; ct < 4; ++ct) {
                f32x4 c = {0.f, 0.f, 0.f, 0.f};
                c = mfma16(w2f[ct][0], a0, c);
                c = mfma16(w2f[ct][1], a1, c);
                const int ci = ch2 * 64 + ct * 16 + q * 4;
                f32x4 v;
                v[0] = (ci + 0 <= t) ? c[0] + b2f[ct][0] : NEG9;
                v[1] = (ci + 1 <= t) ? c[1] + b2f[ct][1] : NEG9;
                v[2] = (ci + 2 <= t) ? c[2] + b2f[ct][2] : NEG9;
                v[3] = (ci + 3 <= t) ? c[3] + b2f[ct][3] : NEG9;
                *(f32x4*)&op[orow + ci] = v;
            }
        }
    }
}

extern "C" void kernel_launch(void* const* d_in, const int* in_sizes, int n_in,
                              void* d_out, int out_size, void* d_ws, size_t ws_size,
                              hipStream_t stream) {
    (void)in_sizes; (void)n_in; (void)d_ws; (void)ws_size;

    prep_kernel<<<53, 256, 0, stream>>>(
        (const float*)d_in[1], (const float*)d_in[2], (const float*)d_in[3],
        (const float*)d_in[4], (const float*)d_in[5], (const float*)d_in[6],
        (const float*)d_in[7], (const float*)d_in[8], (const float*)d_in[9],
        (const float*)d_in[10], (const float*)d_in[11], (const float*)d_in[12],
        (const float*)d_in[13], (const float*)d_in[14], (const float*)d_in[15],
        (const float*)d_in[16], (const float*)d_in[17], (const float*)d_in[18],
        (const float*)d_in[19], (const float*)d_in[20]);

    fused_mlp<<<NB / 128, 512, 0, stream>>>((const u32x4*)d_in[0], (float*)d_out);
}

// Round 14
// 246.209 us; speedup vs baseline: 1.2164x; 1.2164x over previous
//
#include <hip/hip_runtime.h>

#define NB 131072
#define NEG9 -1e9f

typedef __attribute__((ext_vector_type(8))) __bf16 bf16x8;
typedef __attribute__((ext_vector_type(4))) float f32x4;
typedef __attribute__((ext_vector_type(2))) unsigned int u32x2;
typedef __attribute__((ext_vector_type(4))) unsigned int u32x4;

__device__ __forceinline__ f32x4 mfma16(bf16x8 a, bf16x8 b, f32x4 c) {
    return __builtin_amdgcn_mfma_f32_16x16x32_bf16(a, b, c, 0, 0, 0);
}

// pack two floats to bf16x2 (truncation) in ONE v_perm_b32: [hi16(h) | hi16(l)]
__device__ __forceinline__ unsigned pk(float h, float l) {
    return __builtin_amdgcn_perm(__builtin_bit_cast(unsigned, h),
                                 __builtin_bit_cast(unsigned, l), 0x07060302u);
}
__device__ __forceinline__ unsigned pku(unsigned h, unsigned l) {
    return __builtin_amdgcn_perm(h, l, 0x07060302u);
}

// float -> bf16 (RNE) for weight prep
__device__ __forceinline__ unsigned short f2bf(float f) {
    unsigned u = __builtin_bit_cast(unsigned, f);
    u += 0x7fffu + ((u >> 16) & 1u);
    return (unsigned short)(u >> 16);
}

// BN-folded, transposed (n-major, k-contiguous) bf16 weights + fp32 biases.
struct __align__(16) Wspace {
    unsigned short W0t[512][64];
    unsigned short W1t[256][512];
    unsigned short nW1t[64][256];
    unsigned short dW1t[64][256];
    unsigned short nW2t[128][64];
    unsigned short dW2t[128][64];
    float c0[512];
    float c1[256];
    float nb1c[64], db1c[64];
    float nb2c[128], db2c[128];
};

__device__ Wspace g_ws;

// r11 prep: 64x64 LDS-transpose tiles, fully coalesced both sides (kept).
__global__ __launch_bounds__(256) void prep_kernel(
    const float* __restrict__ W0, const float* __restrict__ b0,
    const float* __restrict__ g0, const float* __restrict__ be0,
    const float* __restrict__ rm0, const float* __restrict__ rv0,
    const float* __restrict__ W1, const float* __restrict__ b1,
    const float* __restrict__ g1, const float* __restrict__ be1,
    const float* __restrict__ rm1, const float* __restrict__ rv1,
    const float* __restrict__ nW1, const float* __restrict__ nb1,
    const float* __restrict__ nW2, const float* __restrict__ nb2,
    const float* __restrict__ dW1, const float* __restrict__ db1,
    const float* __restrict__ dW2, const float* __restrict__ db2)
{
    const int b = blockIdx.x;
    const int t = threadIdx.x;

    if (b == 52) {  // bias / BN-constant vectors (all coalesced)
        {   // c0[512]
            int i = t;          g_ws.c0[i] = (b0[i] - rm0[i]) * (g0[i] * rsqrtf(rv0[i] + 1e-5f)) + be0[i];
            i = t + 256;        g_ws.c0[i] = (b0[i] - rm0[i]) * (g0[i] * rsqrtf(rv0[i] + 1e-5f)) + be0[i];
        }
        g_ws.c1[t] = (b1[t] - rm1[t]) * (g1[t] * rsqrtf(rv1[t] + 1e-5f)) + be1[t];
        if (t < 64)  { g_ws.nb1c[t] = nb1[t]; g_ws.db1c[t] = db1[t]; }
        if (t < 128) { g_ws.nb2c[t] = nb2[t]; g_ws.db2c[t] = db2[t]; }
        return;
    }

    const float* src; unsigned short* dst;
    const float* gp = nullptr; const float* rvp = nullptr;
    int sld, dld, k0, n0;
    if (b < 32)      { src = W1;  dst = (unsigned short*)g_ws.W1t;  sld = 256; dld = 512;
                       k0 = (b >> 2) * 64; n0 = (b & 3) * 64; gp = g1; rvp = rv1; }
    else if (b < 40) { src = W0;  dst = (unsigned short*)g_ws.W0t;  sld = 512; dld = 64;
                       k0 = 0; n0 = (b - 32) * 64; gp = g0; rvp = rv0; }
    else if (b < 44) { src = nW1; dst = (unsigned short*)g_ws.nW1t; sld = 64;  dld = 256;
                       k0 = (b - 40) * 64; n0 = 0; }
    else if (b < 48) { src = dW1; dst = (unsigned short*)g_ws.dW1t; sld = 64;  dld = 256;
                       k0 = (b - 44) * 64; n0 = 0; }
    else if (b < 50) { src = nW2; dst = (unsigned short*)g_ws.nW2t; sld = 128; dld = 64;
                       k0 = 0; n0 = (b - 48) * 64; }
    else             { src = dW2; dst = (unsigned short*)g_ws.dW2t; sld = 128; dld = 64;
                       k0 = 0; n0 = (b - 50) * 64; }

    __shared__ unsigned short tile[64][66];

    const int rr = t >> 4;
    const int cc = (t & 15) * 4;

#pragma unroll
    for (int g = 0; g < 4; ++g) {
        const int r = rr + g * 16;
        f32x4 v = *(const f32x4*)&src[(size_t)(k0 + r) * sld + n0 + cc];
        if (gp) {
            f32x4 gv = *(const f32x4*)&gp[n0 + cc];
            f32x4 rv = *(const f32x4*)&rvp[n0 + cc];
            v[0] *= gv[0] * rsqrtf(rv[0] + 1e-5f);
            v[1] *= gv[1] * rsqrtf(rv[1] + 1e-5f);
            v[2] *= gv[2] * rsqrtf(rv[2] + 1e-5f);
            v[3] *= gv[3] * rsqrtf(rv[3] + 1e-5f);
        }
        *(unsigned*)&tile[r][cc]     = (unsigned)f2bf(v[0]) | ((unsigned)f2bf(v[1]) << 16);
        *(unsigned*)&tile[r][cc + 2] = (unsigned)f2bf(v[2]) | ((unsigned)f2bf(v[3]) << 16);
    }
    __syncthreads();

#pragma unroll
    for (int g = 0; g < 4; ++g) {
        const int n = rr + g * 16;
        unsigned o01 = (unsigned)tile[cc + 0][n] | ((unsigned)tile[cc + 1][n] << 16);
        unsigned o23 = (unsigned)tile[cc + 2][n] | ((unsigned)tile[cc + 3][n] << 16);
        u32x2 o = { o01, o23 };
        *(u32x2*)&dst[(size_t)(n0 + n) * dld + k0 + cc] = o;
    }
}

// LEDGER: r15 (128 rows/block) 134->120; r16 (L1 liveness fix) 120->104,
//   bench 255.9 = BEST. r17 (row-split, LDS reads halved) 104->145 —
//   FALSIFIES the LDS-dominance model: trading LDS reads for doubled
//   global weight loads is a big loss (latency exposure + HBM re-fetch,
//   FETCH 26->45). Rule: never trade LDS traffic for global traffic here.
// r18: r16 EXACT revert + ONE anti-spill change: L0 mt-loop unroll capped
//   at 2. r16 spilled ~46MB (WRITE 177 vs 131 ideal): acc1(64) live through
//   ch=1 L0 while the full 8-unroll holds 16 in-flight xq loads. unroll 2
//   caps load pipeline regs; LDS is low-latency so coverage survives.
//   Verification signal: WRITE -> ~140-150MB. If unchanged, spill is
//   elsewhere -> revert to r16 and declare plateau.
__global__ __launch_bounds__(512, 4) void fused_mlp(
    const u32x4* __restrict__ xu, float* __restrict__ out)
{
    __shared__ __align__(16) unsigned short sXs[8 * 128 * 8];   // 16 KB (X, live to end)
    __shared__ __align__(16) unsigned short sH[32 * 128 * 8];   // 64 KB (H0 chunk / H1 / A)

    const int tid = threadIdx.x;
    const int w = tid >> 6;          // wave 0..7
    const int lane = tid & 63;
    const int m = lane & 15;
    const int q = lane >> 4;
    const int qh = q >> 1;
    const int ql = (q & 1) * 4;
    const int row0 = blockIdx.x * 128;

    // ---- stage X -> bf16 granule-major [g][r][8]; 2 units/thread ----
    {
        int r = tid >> 3, g = tid & 7;
#pragma unroll
        for (int hh = 0; hh < 2; ++hh) {
            int rr = r + hh * 64;
            u32x4 v0 = __builtin_nontemporal_load(&xu[(size_t)(row0 + rr) * 16 + g * 2]);
            u32x4 v1 = __builtin_nontemporal_load(&xu[(size_t)(row0 + rr) * 16 + g * 2 + 1]);
            u32x4 p = { pku(v0[1], v0[0]), pku(v0[3], v0[2]), pku(v1[1], v1[0]), pku(v1[3], v1[2]) };
            *(u32x4*)&sXs[(g * 128 + rr) * 8] = p;
        }
    }
    __syncthreads();   // B1

    // ---- layers 0+1, 2 K-chunks of 256; layer-1 partials in regs ----
    f32x4 acc1[2][8];
#pragma unroll
    for (int a = 0; a < 2; ++a)
#pragma unroll
        for (int b = 0; b < 8; ++b) acc1[a][b] = f32x4{0.f, 0.f, 0.f, 0.f};

    for (int ch = 0; ch < 2; ++ch) {
        // layer0: wave w -> chunk cols [w*32,+32), 128 rows.
        // r18: unroll 2 caps in-flight xq loads while acc1 is live.
#pragma unroll
        for (int nt = 0; nt < 2; ++nt) {
            const int gcb = ch * 256 + w * 32 + nt * 16;
            bf16x8 wa0 = *(const bf16x8*)&g_ws.W0t[gcb + m][q * 8];
            bf16x8 wa1 = *(const bf16x8*)&g_ws.W0t[gcb + m][32 + q * 8];
            f32x4 bias = *(const f32x4*)&g_ws.c0[gcb + q * 4];
            const int kg = w * 4 + nt * 2 + qh;    // granule 0..31
#pragma unroll 2
            for (int mt = 0; mt < 8; ++mt) {
                bf16x8 xq0 = *(const bf16x8*)&sXs[(q * 128 + mt * 16 + m) * 8];
                bf16x8 xq1 = *(const bf16x8*)&sXs[((4 + q) * 128 + mt * 16 + m) * 8];
                f32x4 c = {0.f, 0.f, 0.f, 0.f};
                c = mfma16(wa0, xq0, c);
                c = mfma16(wa1, xq1, c);
                u32x2 pw = { pk(fmaxf(c[1] + bias[1], 0.f), fmaxf(c[0] + bias[0], 0.f)),
                             pk(fmaxf(c[3] + bias[3], 0.f), fmaxf(c[2] + bias[2], 0.f)) };
                *(u32x2*)&sH[(kg * 128 + mt * 16 + m) * 8 + ql] = pw;
            }
        }
        __syncthreads();   // B2 / B4

        // layer1 partial: wave w -> out cols [w*32,+32), K-chunk 256.
        // r16: mt-inner with ONE ab live -> minimal pressure.
#pragma unroll
        for (int ks = 0; ks < 8; ++ks) {
            bf16x8 wb0 = *(const bf16x8*)&g_ws.W1t[w * 32 + m][ch * 256 + ks * 32 + q * 8];
            bf16x8 wb1 = *(const bf16x8*)&g_ws.W1t[w * 32 + 16 + m][ch * 256 + ks * 32 + q * 8];
#pragma unroll
            for (int mt = 0; mt < 8; ++mt) {
                bf16x8 ab = *(const bf16x8*)&sH[((ks * 4 + q) * 128 + mt * 16 + m) * 8];
                acc1[0][mt] = mfma16(wb0, ab, acc1[0][mt]);
                acc1[1][mt] = mfma16(wb1, ab, acc1[1][mt]);
            }
        }
        __syncthreads();   // B3 / B5
    }

    // ---- H1 = relu(acc1 + c1) -> sH (whole chunk region dead after B5) ----
#pragma unroll
    for (int nt = 0; nt < 2; ++nt) {
        const int cb = w * 32 + nt * 16;
        f32x4 bias = *(const f32x4*)&g_ws.c1[cb + q * 4];
        const int kg = w * 4 + nt * 2 + qh;    // granule 0..31
#pragma unroll
        for (int mt = 0; mt < 8; ++mt) {
            f32x4 c = acc1[nt][mt];
            u32x2 pw = { pk(fmaxf(c[1] + bias[1], 0.f), fmaxf(c[0] + bias[0], 0.f)),
                         pk(fmaxf(c[3] + bias[3], 0.f), fmaxf(c[2] + bias[2], 0.f)) };
            *(u32x2*)&sH[(kg * 128 + mt * 16 + m) * 8 + ql] = pw;
        }
    }
    __syncthreads();   // B6

    // ---- head layer 1: head = w>>2, cols (w&3)*16..+16, K=256, 128 rows ----
    const int head = w >> 2;
    {
        const int cb = (w & 3) * 16;
        const unsigned short (*Wh)[256] = head ? g_ws.dW1t : g_ws.nW1t;
        const float* bh = head ? g_ws.db1c : g_ws.nb1c;
        f32x4 acc[8];
#pragma unroll
        for (int b = 0; b < 8; ++b) acc[b] = f32x4{0.f, 0.f, 0.f, 0.f};
#pragma unroll
        for (int ks = 0; ks < 8; ++ks) {
            bf16x8 wh = *(const bf16x8*)&Wh[cb + m][ks * 32 + q * 8];
#pragma unroll
            for (int mt = 0; mt < 8; ++mt) {
                bf16x8 ab = *(const bf16x8*)&sH[((ks * 4 + q) * 128 + mt * 16 + m) * 8];
                acc[mt] = mfma16(wh, ab, acc[mt]);
            }
        }
        // all waves' H1 reads must finish before A overlays sH
        __syncthreads();   // B7
        unsigned short* Ah = sH + head * 8192;   // An @ [0,16KB), Ad @ [16KB,32KB)
        f32x4 bias = *(const f32x4*)&bh[cb + q * 4];
        const int kg = (w & 3) * 2 + qh;         // granule 0..7 within head's A
#pragma unroll
        for (int mt = 0; mt < 8; ++mt) {
            f32x4 c = acc[mt];
            u32x2 pw = { pk(fmaxf(c[1] + bias[1], 0.f), fmaxf(c[0] + bias[0], 0.f)),
                         pk(fmaxf(c[3] + bias[3], 0.f), fmaxf(c[2] + bias[2], 0.f)) };
            *(u32x2*)&Ah[(kg * 128 + mt * 16 + m) * 8 + ql] = pw;
        }
    }
    __syncthreads();   // B8

    // ---- head layer 2 + mask + plain dwordx4 stores ----
    {
        const unsigned short (*W2)[64] = head ? g_ws.dW2t : g_ws.nW2t;
        const float* b2 = head ? g_ws.db2c : g_ws.nb2c;
        const unsigned short* Ah = sH + head * 8192;
        float* op = out + (size_t)head * (size_t)NB * 128;

        // thresholds via PROVEN sXs path: granule 7 elems 4,5 = cols 60,61
        // (class ids 0..127 exact in bf16); sXs untouched throughout
        int thr[8];
#pragma unroll
        for (int mt = 0; mt < 8; ++mt) {
            unsigned tv = *(const unsigned*)&sXs[(7 * 128 + mt * 16 + m) * 8 + 4];
            thr[mt] = (int)__builtin_bit_cast(float, head ? (tv & 0xffff0000u) : (tv << 16));
        }
#pragma unroll
        for (int ct = 0; ct < 2; ++ct) {
            const int ocb = (w & 3) * 32 + ct * 16;
            bf16x8 w0 = *(const bf16x8*)&W2[ocb + m][q * 8];
            bf16x8 w1 = *(const bf16x8*)&W2[ocb + m][32 + q * 8];
            f32x4 bias = *(const f32x4*)&b2[ocb + q * 4];
#pragma unroll
            for (int mt = 0; mt < 8; ++mt) {
                bf16x8 a0 = *(const bf16x8*)&Ah[(q * 128 + mt * 16 + m) * 8];
                bf16x8 a1 = *(const bf16x8*)&Ah[((4 + q) * 128 + mt * 16 + m) * 8];
                f32x4 c = {0.f, 0.f, 0.f, 0.f};
                c = mfma16(w0, a0, c);
                c = mfma16(w1, a1, c);
                const int ci = ocb + q * 4;
                const int t = thr[mt];
                f32x4 v;
                v[0] = (ci + 0 <= t) ? c[0] + bias[0] : NEG9;
                v[1] = (ci + 1 <= t) ? c[1] + bias[1] : NEG9;
                v[2] = (ci + 2 <= t) ? c[2] + bias[2] : NEG9;
                v[3] = (ci + 3 <= t) ? c[3] + bias[3] : NEG9;
                *(f32x4*)&op[(size_t)(row0 + mt * 16 + m) * 128 + ci] = v;
            }
        }
    }
}

extern "C" void kernel_launch(void* const* d_in, const int* in_sizes, int n_in,
                              void* d_out, int out_size, void* d_ws, size_t ws_size,
                              hipStream_t stream) {
    (void)in_sizes; (void)n_in; (void)d_ws; (void)ws_size;

    prep_kernel<<<53, 256, 0, stream>>>(
        (const float*)d_in[1], (const float*)d_in[2], (const float*)d_in[3],
        (const float*)d_in[4], (const float*)d_in[5], (const float*)d_in[6],
        (const float*)d_in[7], (const float*)d_in[8], (const float*)d_in[9],
        (const float*)d_in[10], (const float*)d_in[11], (const float*)d_in[12],
        (const float*)d_in[13], (const float*)d_in[14], (const float*)d_in[15],
        (const float*)d_in[16], (const float*)d_in[17], (const float*)d_in[18],
        (const float*)d_in[19], (const float*)d_in[20]);

    fused_mlp<<<NB / 128, 512, 0, stream>>>((const u32x4*)d_in[0], (float*)d_out);
}